// Round 2
// baseline (2162.332 us; speedup 1.0000x reference)
//
#include <hip/hip_runtime.h>

// WindowAttention2d: B=8, C=96, H=W=256, WIN=8, SHIFT=4, HEADS=3, dh=32.
// Global I/O is fp32 (reference dtypes); LDS intermediates bf16, fp32 accum.
// One workgroup (256 threads = 4 waves) per 8x8 window; 8192 windows.
// Shift is a pure index roll: read/write x[(i*8+tr+4)&255][(j*8+tc+4)&255].
// LDS: Y bf16 [64][136] (fp32 S 64x68 overlaid after QKV), Q/K/V bf16 [64][104].
// Total 57344 B -> 2 blocks/CU.

#define SHIFT_ 4
#define Cdim 96
#define HH 256
#define WW2 256
#define YS 136   // ushort stride, 8*17
#define QS 104   // ushort stride, 8*13
#define SS 68    // float stride, 4*17 (overlay on sY: 64*68*4 == 64*136*2)

typedef unsigned short u16;
typedef unsigned int u32;

__device__ __forceinline__ float bf2f(u16 u) {
  union { u32 i; float f; } v; v.i = ((u32)u) << 16; return v.f;
}
__device__ __forceinline__ u16 f2bf(float f) {
  union { float f; u32 i; } v; v.f = f;
  u32 r = v.i + 0x7fffu + ((v.i >> 16) & 1u);   // RNE (finite values only)
  return (u16)(r >> 16);
}
__device__ __forceinline__ void unpack8(uint4 v, float* f) {
  union { u32 i; float f; } t;
  t.i = v.x << 16;         f[0] = t.f;
  t.i = v.x & 0xffff0000u; f[1] = t.f;
  t.i = v.y << 16;         f[2] = t.f;
  t.i = v.y & 0xffff0000u; f[3] = t.f;
  t.i = v.z << 16;         f[4] = t.f;
  t.i = v.z & 0xffff0000u; f[5] = t.f;
  t.i = v.w << 16;         f[6] = t.f;
  t.i = v.w & 0xffff0000u; f[7] = t.f;
}
__device__ __forceinline__ uint4 pack8(const float* f) {
  uint4 v;
  v.x = (u32)f2bf(f[0]) | ((u32)f2bf(f[1]) << 16);
  v.y = (u32)f2bf(f[2]) | ((u32)f2bf(f[3]) << 16);
  v.z = (u32)f2bf(f[4]) | ((u32)f2bf(f[5]) << 16);
  v.w = (u32)f2bf(f[6]) | ((u32)f2bf(f[7]) << 16);
  return v;
}
__device__ __forceinline__ void loadw8(const float* p, float* w) {
  float4 a = *(const float4*)(p);
  float4 b = *(const float4*)(p + 4);
  w[0]=a.x; w[1]=a.y; w[2]=a.z; w[3]=a.w;
  w[4]=b.x; w[5]=b.y; w[6]=b.z; w[7]=b.w;
}

extern "C" __global__ __launch_bounds__(256, 2)
void winattn_kernel(const float* __restrict__ x,
                    const float* __restrict__ lng,  const float* __restrict__ lnb,
                    const float* __restrict__ wqkv, const float* __restrict__ bqkv,
                    const float* __restrict__ wout, const float* __restrict__ bout,
                    const float* __restrict__ wproj,const float* __restrict__ bproj,
                    float* __restrict__ out) {
  __shared__ u16 sY[64 * YS];
  __shared__ u16 sQ[64 * QS];
  __shared__ u16 sK[64 * QS];
  __shared__ u16 sV[64 * QS];
  float* sS = (float*)sY;  // S/P overlay, valid after QKV consumed Y

  const int tid  = threadIdx.x;
  const int lane = tid & 63;
  const int wv   = tid >> 6;

  const int n  = blockIdx.x;
  const int b  = n >> 10;
  const int wi = n & 1023;
  const int iw = wi >> 5;
  const int jw = wi & 31;
  const int r0 = iw * 8 + SHIFT_;
  const int c0 = jw * 8 + SHIFT_;

  // ---- Phase 1: load window (fp32 -> bf16). 96ch x 8rows x 2 col-quads.
  // shift=4 => 4-col quads never straddle the mod-256 wrap.
  for (int it = 0; it < 6; ++it) {
    int task = it * 256 + tid;
    int ch = task >> 4;
    int tr = (task >> 1) & 7;
    int q  = task & 1;
    int r = (r0 + tr) & 255;
    int c = (c0 + q * 4) & 255;
    float4 v = *(const float4*)(x + (((size_t)(b * Cdim + ch) * HH + r) * WW2 + c));
    int t = tr * 8 + q * 4;
    sY[(t + 0) * YS + ch] = f2bf(v.x);
    sY[(t + 1) * YS + ch] = f2bf(v.y);
    sY[(t + 2) * YS + ch] = f2bf(v.z);
    sY[(t + 3) * YS + ch] = f2bf(v.w);
  }
  __syncthreads();

  // ---- Phase 2: LayerNorm over C=96 per token; 4 threads/token.
  {
    const int t = tid >> 2;
    const int part = tid & 3;
    const int base = part * 24;
    float v[24];
#pragma unroll
    for (int k = 0; k < 3; ++k)
      unpack8(*(const uint4*)(sY + t * YS + base + k * 8), v + k * 8);
    float sum = 0.f, sq = 0.f;
#pragma unroll
    for (int i = 0; i < 24; ++i) { sum += v[i]; sq += v[i] * v[i]; }
    sum += __shfl_xor(sum, 1); sq += __shfl_xor(sq, 1);
    sum += __shfl_xor(sum, 2); sq += __shfl_xor(sq, 2);
    float mu  = sum * (1.f / 96.f);
    float var = sq * (1.f / 96.f) - mu * mu;
    float rs  = rsqrtf(var + 1e-5f);
    float o[24];
#pragma unroll
    for (int i = 0; i < 24; ++i) {
      int ch = base + i;
      o[i] = (v[i] - mu) * rs * lng[ch] + lnb[ch];
    }
#pragma unroll
    for (int k = 0; k < 3; ++k)
      *(uint4*)(sY + t * YS + base + k * 8) = pack8(o + k * 8);
  }
  __syncthreads();

  // ---- Phase 3: QKV = Y @ Wqkv^T + b. Wave wv owns j in [wv*72, wv*72+72).
  {
    const int t = lane;
#pragma unroll 1
    for (int cb = 0; cb < 72; cb += 8) {
      const int jb = __builtin_amdgcn_readfirstlane(wv * 72 + cb);
      float acc[8];
#pragma unroll
      for (int jj = 0; jj < 8; ++jj) acc[jj] = bqkv[jb + jj];
      for (int ch = 0; ch < 96; ch += 8) {
        float y[8]; unpack8(*(const uint4*)(sY + t * YS + ch), y);
#pragma unroll
        for (int jj = 0; jj < 8; ++jj) {
          float w[8]; loadw8(wqkv + (jb + jj) * 96 + ch, w);
#pragma unroll
          for (int k = 0; k < 8; ++k) acc[jj] += y[k] * w[k];
        }
      }
      u16* dst; int col; float scale;
      if (jb < 96)       { dst = sQ; col = jb;       scale = 0.17677669529663689f; } // 1/sqrt(32) folded into Q
      else if (jb < 192) { dst = sK; col = jb - 96;  scale = 1.f; }
      else               { dst = sV; col = jb - 192; scale = 1.f; }
      float o[8];
#pragma unroll
      for (int jj = 0; jj < 8; ++jj) o[jj] = acc[jj] * scale;
      *(uint4*)(dst + t * QS + col) = pack8(o);
    }
  }
  __syncthreads();

  // ---- Phase 4: per-head attention. S overlays dead Y buffer.
#pragma unroll 1
  for (int h = 0; h < 3; ++h) {
    // S[l][m] = sum_d Q[l][h*32+d] * K[m][h*32+d]; wave owns 16 m-cols.
    {
      const int l = lane;
#pragma unroll 1
      for (int cb = 0; cb < 16; cb += 8) {
        const int mb = __builtin_amdgcn_readfirstlane(wv * 16 + cb);
        float acc[8] = {0.f,0.f,0.f,0.f,0.f,0.f,0.f,0.f};
        for (int d = 0; d < 32; d += 8) {
          float q[8]; unpack8(*(const uint4*)(sQ + l * QS + h * 32 + d), q);
#pragma unroll
          for (int jj = 0; jj < 8; ++jj) {
            float k8[8]; unpack8(*(const uint4*)(sK + (mb + jj) * QS + h * 32 + d), k8);
#pragma unroll
            for (int k = 0; k < 8; ++k) acc[jj] += q[k] * k8[k];
          }
        }
        *(float4*)(&sS[l * SS + mb])     = make_float4(acc[0], acc[1], acc[2], acc[3]);
        *(float4*)(&sS[l * SS + mb + 4]) = make_float4(acc[4], acc[5], acc[6], acc[7]);
      }
    }
    __syncthreads();
    // softmax rows; 4 threads/row, 16 cols each.
    {
      const int row = tid >> 2;
      const int qr  = tid & 3;
      float v[16];
#pragma unroll
      for (int k = 0; k < 4; ++k) {
        float4 p = *(const float4*)(&sS[row * SS + qr * 16 + k * 4]);
        v[k*4+0]=p.x; v[k*4+1]=p.y; v[k*4+2]=p.z; v[k*4+3]=p.w;
      }
      float mx = v[0];
#pragma unroll
      for (int i = 1; i < 16; ++i) mx = fmaxf(mx, v[i]);
      mx = fmaxf(mx, __shfl_xor(mx, 1));
      mx = fmaxf(mx, __shfl_xor(mx, 2));
      float sum = 0.f;
#pragma unroll
      for (int i = 0; i < 16; ++i) { v[i] = __expf(v[i] - mx); sum += v[i]; }
      sum += __shfl_xor(sum, 1);
      sum += __shfl_xor(sum, 2);
      float inv = 1.0f / sum;
#pragma unroll
      for (int k = 0; k < 4; ++k) {
        float4 p = make_float4(v[k*4+0]*inv, v[k*4+1]*inv, v[k*4+2]*inv, v[k*4+3]*inv);
        *(float4*)(&sS[row * SS + qr * 16 + k * 4]) = p;
      }
    }
    __syncthreads();
    // O_h[l][d] = sum_m P[l][m] V[m][h*32+d]; wave owns 8 d's. Write into sQ slice h.
    {
      const int l = lane;
      const int db = __builtin_amdgcn_readfirstlane(wv * 8);
      float acc[8] = {0.f,0.f,0.f,0.f,0.f,0.f,0.f,0.f};
      for (int m = 0; m < 64; m += 4) {
        float4 p4 = *(const float4*)(&sS[l * SS + m]);
        float pv[4] = {p4.x, p4.y, p4.z, p4.w};
#pragma unroll
        for (int mm = 0; mm < 4; ++mm) {
          float v8[8]; unpack8(*(const uint4*)(sV + (m + mm) * QS + h * 32 + db), v8);
#pragma unroll
          for (int jj = 0; jj < 8; ++jj) acc[jj] += pv[mm] * v8[jj];
        }
      }
      *(uint4*)(sQ + l * QS + h * 32 + db) = pack8(acc);
    }
    __syncthreads();
  }

  // ---- Phase 5: O2 = O @ Wout^T + bout  (sQ -> sK). Wave owns 24 j's.
  {
    const int t = lane;
#pragma unroll 1
    for (int cb = 0; cb < 24; cb += 8) {
      const int jb = __builtin_amdgcn_readfirstlane(wv * 24 + cb);
      float acc[8];
#pragma unroll
      for (int jj = 0; jj < 8; ++jj) acc[jj] = bout[jb + jj];
      for (int ch = 0; ch < 96; ch += 8) {
        float o8[8]; unpack8(*(const uint4*)(sQ + t * QS + ch), o8);
#pragma unroll
        for (int jj = 0; jj < 8; ++jj) {
          float w[8]; loadw8(wout + (jb + jj) * 96 + ch, w);
#pragma unroll
          for (int k = 0; k < 8; ++k) acc[jj] += o8[k] * w[k];
        }
      }
      *(uint4*)(sK + t * QS + jb) = pack8(acc);
    }
  }
  __syncthreads();

  // ---- Phase 6: out = O2 @ Wproj^T + bproj -> global (fp32), same coords as load.
  {
    const int t = lane;
    const int tr = t >> 3, tc = t & 7;
    const int r = (r0 + tr) & 255;
    const int c = (c0 + tc) & 255;
    float* outp = out + (size_t)b * Cdim * HH * WW2 + (size_t)r * WW2 + c;
#pragma unroll 1
    for (int cb = 0; cb < 24; cb += 8) {
      const int jb = __builtin_amdgcn_readfirstlane(wv * 24 + cb);
      float acc[8];
#pragma unroll
      for (int jj = 0; jj < 8; ++jj) acc[jj] = bproj[jb + jj];
      for (int ch = 0; ch < 96; ch += 8) {
        float o8[8]; unpack8(*(const uint4*)(sK + t * QS + ch), o8);
#pragma unroll
        for (int jj = 0; jj < 8; ++jj) {
          float w[8]; loadw8(wproj + (jb + jj) * 96 + ch, w);
#pragma unroll
          for (int k = 0; k < 8; ++k) acc[jj] += o8[k] * w[k];
        }
      }
#pragma unroll
      for (int jj = 0; jj < 8; ++jj)
        outp[(size_t)(jb + jj) * (HH * WW2)] = acc[jj];
    }
  }
}

extern "C" void kernel_launch(void* const* d_in, const int* in_sizes, int n_in,
                              void* d_out, int out_size, void* d_ws, size_t ws_size,
                              hipStream_t stream) {
  (void)in_sizes; (void)n_in; (void)out_size; (void)d_ws; (void)ws_size;
  const float* x     = (const float*)d_in[0];
  const float* lng   = (const float*)d_in[1];
  const float* lnb   = (const float*)d_in[2];
  const float* wqkv  = (const float*)d_in[3];
  const float* bqkv  = (const float*)d_in[4];
  const float* wout  = (const float*)d_in[5];
  const float* bout  = (const float*)d_in[6];
  const float* wproj = (const float*)d_in[7];
  const float* bproj = (const float*)d_in[8];
  float* out = (float*)d_out;
  dim3 grid(8192), block(256);
  hipLaunchKernelGGL(winattn_kernel, grid, block, 0, stream,
                     x, lng, lnb, wqkv, bqkv, wout, bout, wproj, bproj, out);
}

// Round 3
// 716.157 us; speedup vs baseline: 3.0194x; 3.0194x over previous
//
#include <hip/hip_runtime.h>

// WindowAttention2d: B=8, C=96, H=W=256, WIN=8, SHIFT=4, HEADS=3, dh=32.
// fp32 global I/O; bf16 MFMA (16x16x32) for all matmuls, fp32 accum.
// One workgroup (256 thr = 4 waves) per 8x8 window; wave w owns token rows
// 16w..16w+15 (the M-tile). Weights pre-swizzled to B-fragment order in d_ws.
// MFMA layouts (gfx950, HW-verified per guide):
//   A[lane&15][quad*8+j]  B[quad*8+j][lane&15]  C/D: row=quad*4+reg, col=lane&15
// LDS 53760B (Y->P, Q->O, K->O2 reuse) -> 2 blocks/CU.

#define SHIFT_ 4
#define HH 256
#define YS 104   // u16 stride for Y/Q/K/O/O2/P rows (16B-aligned, 2-way-bank-free)
#define VS 72    // u16 stride for Vt rows [ch][token]

typedef unsigned short u16;
typedef unsigned int u32;
typedef short bf16x8 __attribute__((ext_vector_type(8)));
typedef float f32x4 __attribute__((ext_vector_type(4)));

__device__ __forceinline__ u16 f2bf(float f) {
  union { float f; u32 i; } v; v.f = f;
  u32 r = v.i + 0x7fffu + ((v.i >> 16) & 1u);   // RNE (finite only)
  return (u16)(r >> 16);
}
__device__ __forceinline__ void unpack8(uint4 v, float* f) {
  union { u32 i; float f; } t;
  t.i = v.x << 16;         f[0] = t.f;
  t.i = v.x & 0xffff0000u; f[1] = t.f;
  t.i = v.y << 16;         f[2] = t.f;
  t.i = v.y & 0xffff0000u; f[3] = t.f;
  t.i = v.z << 16;         f[4] = t.f;
  t.i = v.z & 0xffff0000u; f[5] = t.f;
  t.i = v.w << 16;         f[6] = t.f;
  t.i = v.w & 0xffff0000u; f[7] = t.f;
}
__device__ __forceinline__ uint4 pack8(const float* f) {
  uint4 v;
  v.x = (u32)f2bf(f[0]) | ((u32)f2bf(f[1]) << 16);
  v.y = (u32)f2bf(f[2]) | ((u32)f2bf(f[3]) << 16);
  v.z = (u32)f2bf(f[4]) | ((u32)f2bf(f[5]) << 16);
  v.w = (u32)f2bf(f[6]) | ((u32)f2bf(f[7]) << 16);
  return v;
}

// ---- prep: swizzle weights (row-major [n][k], fp32) into bf16 B-fragments.
// Fragment tile (nt,kt): u16 ws[(tileIdx*64 + lane)*8 + j] = W[nt*16+(lane&15)][kt*32+(lane>>4)*8+j]
// tiles: wqkv 0..53 (nt 0..17 x kt 0..2), wout 54..71, wproj 72..89.
extern "C" __global__ void prep_kernel(const float* __restrict__ wqkv,
                                       const float* __restrict__ wout,
                                       const float* __restrict__ wproj,
                                       u16* __restrict__ ws) {
  const int tile = blockIdx.x;
  const int lane = threadIdx.x;
  const float* src; int t;
  if (tile < 54)      { src = wqkv; t = tile; }
  else if (tile < 72) { src = wout; t = tile - 54; }
  else                { src = wproj; t = tile - 72; }
  const int nt = t / 3, kt = t % 3;
  const int n = nt * 16 + (lane & 15);
  const int k = kt * 32 + ((lane >> 4) * 8);
  const float* p = src + n * 96 + k;
  float f[8];
  float4 a = *(const float4*)p, b2 = *(const float4*)(p + 4);
  f[0]=a.x; f[1]=a.y; f[2]=a.z; f[3]=a.w; f[4]=b2.x; f[5]=b2.y; f[6]=b2.z; f[7]=b2.w;
  *(uint4*)(ws + (size_t)tile * 512 + lane * 8) = pack8(f);
}

extern "C" __global__ __launch_bounds__(256, 2)
void winattn_kernel(const float* __restrict__ x,
                    const float* __restrict__ lng,  const float* __restrict__ lnb,
                    const float* __restrict__ bqkv,
                    const float* __restrict__ bout, const float* __restrict__ bproj,
                    const u16* __restrict__ wsfrag,
                    float* __restrict__ out) {
  __shared__ u16 sY[64 * YS];   // Y, then P (per-head, wave-local rows)
  __shared__ u16 sQ[64 * YS];   // Q, then O
  __shared__ u16 sK[64 * YS];   // K, then O2
  __shared__ u16 sVt[96 * VS];  // V transposed [ch][token]

  const int tid  = threadIdx.x;
  const int lane = tid & 63;
  const int m0   = __builtin_amdgcn_readfirstlane((tid >> 6) * 16);
  const int l15  = lane & 15;
  const int qd   = lane >> 4;
  const int row  = m0 + l15;           // this lane's A-fragment row

  const int n  = blockIdx.x;
  const int b  = n >> 10;
  const int wi = n & 1023;
  const int r0 = (wi >> 5) * 8 + SHIFT_;
  const int c0 = (wi & 31) * 8 + SHIFT_;

  // ---- Phase 1: load window fp32 -> bf16 LDS [token][ch].
  for (int it = 0; it < 6; ++it) {
    int task = it * 256 + tid;
    int ch = task >> 4;
    int tr = (task >> 1) & 7;
    int q  = task & 1;
    int r = (r0 + tr) & 255;
    int c = (c0 + q * 4) & 255;
    float4 v = *(const float4*)(x + (((size_t)(b * 96 + ch) * HH + r) * HH + c));
    int t = tr * 8 + q * 4;
    sY[(t + 0) * YS + ch] = f2bf(v.x);
    sY[(t + 1) * YS + ch] = f2bf(v.y);
    sY[(t + 2) * YS + ch] = f2bf(v.z);
    sY[(t + 3) * YS + ch] = f2bf(v.w);
  }
  __syncthreads();

  // ---- Phase 2: LayerNorm, 4 threads/token (wave-local tokens).
  {
    const int t = tid >> 2;
    const int base = (tid & 3) * 24;
    float v[24];
#pragma unroll
    for (int k = 0; k < 3; ++k)
      unpack8(*(const uint4*)(sY + t * YS + base + k * 8), v + k * 8);
    float sum = 0.f, sq = 0.f;
#pragma unroll
    for (int i = 0; i < 24; ++i) { sum += v[i]; sq += v[i] * v[i]; }
    sum += __shfl_xor(sum, 1); sq += __shfl_xor(sq, 1);
    sum += __shfl_xor(sum, 2); sq += __shfl_xor(sq, 2);
    float mu  = sum * (1.f / 96.f);
    float var = sq * (1.f / 96.f) - mu * mu;
    float rs  = rsqrtf(var + 1e-5f);
    float o[24];
#pragma unroll
    for (int i = 0; i < 24; ++i)
      o[i] = (v[i] - mu) * rs * lng[base + i] + lnb[base + i];
#pragma unroll
    for (int k = 0; k < 3; ++k)
      *(uint4*)(sY + t * YS + base + k * 8) = pack8(o + k * 8);
  }
  __syncthreads();

  const bf16x8* frag = (const bf16x8*)wsfrag;

  // ---- Phase 3: QKV = Y @ Wqkv^T + b (M=64,N=288,K=96). 18 N-tiles.
  {
    bf16x8 aY[3];
#pragma unroll
    for (int kt = 0; kt < 3; ++kt)
      aY[kt] = *(const bf16x8*)(sY + row * YS + kt * 32 + qd * 8);
#pragma unroll 1
    for (int nt = 0; nt < 18; ++nt) {
      float bias = bqkv[nt * 16 + l15];
      f32x4 c = {bias, bias, bias, bias};
#pragma unroll
      for (int kt = 0; kt < 3; ++kt)
        c = __builtin_amdgcn_mfma_f32_16x16x32_bf16(aY[kt], frag[(nt * 3 + kt) * 64 + lane], c, 0, 0, 0);
      if (nt < 6) {            // Q (scaled by 1/sqrt(32))
        int col = nt * 16 + l15;
#pragma unroll
        for (int r = 0; r < 4; ++r)
          sQ[(m0 + qd * 4 + r) * YS + col] = f2bf(c[r] * 0.17677669529663689f);
      } else if (nt < 12) {    // K
        int col = (nt - 6) * 16 + l15;
#pragma unroll
        for (int r = 0; r < 4; ++r)
          sK[(m0 + qd * 4 + r) * YS + col] = f2bf(c[r]);
      } else {                 // V -> transposed [ch][token]
        int ch = (nt - 12) * 16 + l15;
        u32 lo = (u32)f2bf(c[0]) | ((u32)f2bf(c[1]) << 16);
        u32 hi = (u32)f2bf(c[2]) | ((u32)f2bf(c[3]) << 16);
        *(uint2*)(sVt + ch * VS + m0 + qd * 4) = make_uint2(lo, hi);
      }
    }
  }
  __syncthreads();

  // ---- Phase 4: attention per head; softmax in registers; P via LDS (sY).
  f32x4 oAcc[6];
#pragma unroll
  for (int i = 0; i < 6; ++i) oAcc[i] = (f32x4){0.f, 0.f, 0.f, 0.f};
#pragma unroll 1
  for (int h = 0; h < 3; ++h) {
    // S = Q @ K^T (M=64,N=64,K=32); wave's M-tile, 4 N-tiles.
    bf16x8 aq = *(const bf16x8*)(sQ + row * YS + h * 32 + qd * 8);
    f32x4 s[4];
#pragma unroll
    for (int nt = 0; nt < 4; ++nt) {
      bf16x8 bk = *(const bf16x8*)(sK + (nt * 16 + l15) * YS + h * 32 + qd * 8);
      f32x4 z = {0.f, 0.f, 0.f, 0.f};
      s[nt] = __builtin_amdgcn_mfma_f32_16x16x32_bf16(aq, bk, z, 0, 0, 0);
    }
    // softmax: row r = m0+qd*4+r lives in the 16-lane group (same qd); cols nt*16+l15.
#pragma unroll
    for (int r = 0; r < 4; ++r) {
      float mx = fmaxf(fmaxf(s[0][r], s[1][r]), fmaxf(s[2][r], s[3][r]));
      mx = fmaxf(mx, __shfl_xor(mx, 1));
      mx = fmaxf(mx, __shfl_xor(mx, 2));
      mx = fmaxf(mx, __shfl_xor(mx, 4));
      mx = fmaxf(mx, __shfl_xor(mx, 8));
      float e0 = __expf(s[0][r] - mx), e1 = __expf(s[1][r] - mx);
      float e2 = __expf(s[2][r] - mx), e3 = __expf(s[3][r] - mx);
      float sum = e0 + e1 + e2 + e3;
      sum += __shfl_xor(sum, 1);
      sum += __shfl_xor(sum, 2);
      sum += __shfl_xor(sum, 4);
      sum += __shfl_xor(sum, 8);
      float inv = 1.0f / sum;
      s[0][r] = e0 * inv; s[1][r] = e1 * inv; s[2][r] = e2 * inv; s[3][r] = e3 * inv;
    }
    // P -> LDS (sY region), row-major [l][m], wave-local rows.
#pragma unroll
    for (int nt = 0; nt < 4; ++nt)
#pragma unroll
      for (int r = 0; r < 4; ++r)
        sY[(m0 + qd * 4 + r) * YS + nt * 16 + l15] = f2bf(s[nt][r]);
    __syncthreads();
    // O_h = P @ V (M=64,N=32,K=64): A from sY(P), B from sVt.
    bf16x8 ap[2];
#pragma unroll
    for (int kt = 0; kt < 2; ++kt)
      ap[kt] = *(const bf16x8*)(sY + row * YS + kt * 32 + qd * 8);
#pragma unroll
    for (int nt = 0; nt < 2; ++nt)
#pragma unroll
      for (int kt = 0; kt < 2; ++kt) {
        bf16x8 bv = *(const bf16x8*)(sVt + (h * 32 + nt * 16 + l15) * VS + kt * 32 + qd * 8);
        oAcc[h * 2 + nt] = __builtin_amdgcn_mfma_f32_16x16x32_bf16(ap[kt], bv, oAcc[h * 2 + nt], 0, 0, 0);
      }
  }

  // ---- O -> sQ (reuse; wave-local rows), row-major [token][ch].
#pragma unroll
  for (int i = 0; i < 6; ++i) {
    int col = i * 16 + l15;
#pragma unroll
    for (int r = 0; r < 4; ++r)
      sQ[(m0 + qd * 4 + r) * YS + col] = f2bf(oAcc[i][r]);
  }
  __syncthreads();

  // ---- Phase 5: O2 = O @ Wout^T + bout (sQ -> sK).
  {
    bf16x8 aO[3];
#pragma unroll
    for (int kt = 0; kt < 3; ++kt)
      aO[kt] = *(const bf16x8*)(sQ + row * YS + kt * 32 + qd * 8);
#pragma unroll 1
    for (int nt = 0; nt < 6; ++nt) {
      float bias = bout[nt * 16 + l15];
      f32x4 c = {bias, bias, bias, bias};
#pragma unroll
      for (int kt = 0; kt < 3; ++kt)
        c = __builtin_amdgcn_mfma_f32_16x16x32_bf16(aO[kt], frag[(54 + nt * 3 + kt) * 64 + lane], c, 0, 0, 0);
      int col = nt * 16 + l15;
#pragma unroll
      for (int r = 0; r < 4; ++r)
        sK[(m0 + qd * 4 + r) * YS + col] = f2bf(c[r]);
    }
  }
  __syncthreads();

  // ---- Phase 6: out = O2 @ Wproj^T + bproj -> global float4 stores.
  {
    bf16x8 aO2[3];
#pragma unroll
    for (int kt = 0; kt < 3; ++kt)
      aO2[kt] = *(const bf16x8*)(sK + row * YS + kt * 32 + qd * 8);
    const int t0 = m0 + qd * 4;          // 4 consecutive tokens (same image row)
    const int rr = (r0 + (t0 >> 3)) & 255;
    const int cs = (c0 + (t0 & 7)) & 255;
#pragma unroll 1
    for (int nt = 0; nt < 6; ++nt) {
      float bias = bproj[nt * 16 + l15];
      f32x4 c = {bias, bias, bias, bias};
#pragma unroll
      for (int kt = 0; kt < 3; ++kt)
        c = __builtin_amdgcn_mfma_f32_16x16x32_bf16(aO2[kt], frag[(72 + nt * 3 + kt) * 64 + lane], c, 0, 0, 0);
      int ch = nt * 16 + l15;
      *(float4*)(out + ((size_t)(b * 96 + ch) * HH + rr) * HH + cs) =
          make_float4(c[0], c[1], c[2], c[3]);
    }
  }
}

extern "C" void kernel_launch(void* const* d_in, const int* in_sizes, int n_in,
                              void* d_out, int out_size, void* d_ws, size_t ws_size,
                              hipStream_t stream) {
  (void)in_sizes; (void)n_in; (void)out_size; (void)ws_size;
  const float* x     = (const float*)d_in[0];
  const float* lng   = (const float*)d_in[1];
  const float* lnb   = (const float*)d_in[2];
  const float* wqkv  = (const float*)d_in[3];
  const float* bqkv  = (const float*)d_in[4];
  const float* wout  = (const float*)d_in[5];
  const float* bout  = (const float*)d_in[6];
  const float* wproj = (const float*)d_in[7];
  const float* bproj = (const float*)d_in[8];
  float* out = (float*)d_out;
  u16* ws = (u16*)d_ws;

  hipLaunchKernelGGL(prep_kernel, dim3(90), dim3(64), 0, stream, wqkv, wout, wproj, ws);
  hipLaunchKernelGGL(winattn_kernel, dim3(8192), dim3(256), 0, stream,
                     x, lng, lnb, bqkv, bout, bproj, (const u16*)ws, out);
}